// Round 1
// baseline (195.859 us; speedup 1.0000x reference)
//
#include <hip/hip_runtime.h>

#define F_IN 165
#define HID  32

// MFMA fragment types (gfx950: v_mfma_f32_16x16x32_bf16 takes v8bf16)
typedef __attribute__((ext_vector_type(8))) __bf16 bf16x8;
typedef __attribute__((ext_vector_type(4))) float  f32x4;

__device__ __forceinline__ float fast_sigmoid(float x) {
    return __builtin_amdgcn_rcpf(1.f + __builtin_amdgcn_exp2f(-1.4426950408889634f * x));
}
__device__ __forceinline__ float fast_tanh(float x) {
    // tanh(x) = 1 - 2/(exp(2x)+1); saturates correctly at +/-inf
    return 1.f - 2.f * __builtin_amdgcn_rcpf(1.f + __builtin_amdgcn_exp2f(2.8853900817779268f * x));
}

struct KParams {
    const float *x, *h, *c;
    const float *W0, *W1, *W2, *W3;
    const float *b0, *b1, *b2, *b3;
    const float *Wc0, *Wc1, *Wc2, *Wc3;
    const float *bc0, *bc1, *bc2, *bc3;
    const float *Wl, *bl;
    float *y, *h0o, *c0o;
    int n;        // node count
    int ntiles;   // ceil(n/64)
};

// LDS layout (aliased):
//   phase A (staging+MFMA): sx = [64][192] bf16, swizzled (24576 B)
//                           sh = [64][32]  bf16, swizzled (4096 B at +24576)
//   phase B (gate combine):  sg = [4][64][33] f32 (33792 B, aliases sx/sh)
#define SMEM_BYTES 33792
#define SH_OFF     24576

__global__ __launch_bounds__(256, 3) void gclstm_kernel(KParams p) {
    __shared__ char smem[SMEM_BYTES];
    __bf16* sx = (__bf16*)smem;
    __bf16* sh = (__bf16*)(smem + SH_OFF);
    float*  sg = (float*)smem;

    const int tid = threadIdx.x;
    const int w   = tid >> 6;    // wave id == gate id (0=i,1=f,2=g,3=o)
    const int l   = tid & 63;
    const int cl  = l & 15;      // col within 16 (A-row / B-col / D-col index)
    const int q   = l >> 4;      // lane quarter (k-group)

    const float* W  = w==0 ? p.W0  : w==1 ? p.W1  : w==2 ? p.W2  : p.W3;
    const float* B  = w==0 ? p.b0  : w==1 ? p.b1  : w==2 ? p.b2  : p.b3;
    const float* Wc = w==0 ? p.Wc0 : w==1 ? p.Wc1 : w==2 ? p.Wc2 : p.Wc3;
    const float* Bc = w==0 ? p.bc0 : w==1 ? p.bc1 : w==2 ? p.bc2 : p.bc3;
    const bool is_tanh_gate = (w == 2);

    // ---- W fragments in registers (per wave: its gate's [165->192][32] as bf16) ----
    // B-frag layout: lane holds B[k = ks*32 + q*8 + j][col = hf*16 + cl]
    bf16x8 bw[6][2];
    bf16x8 bwc[2];
    float  bias[2];
#pragma unroll
    for (int ks = 0; ks < 6; ++ks)
#pragma unroll
        for (int hf = 0; hf < 2; ++hf)
#pragma unroll
            for (int j = 0; j < 8; ++j) {
                int k = ks * 32 + q * 8 + j;
                float v = (k < F_IN) ? W[k * HID + hf * 16 + cl] : 0.f;
                bw[ks][hf][j] = (__bf16)v;
            }
#pragma unroll
    for (int hf = 0; hf < 2; ++hf) {
#pragma unroll
        for (int j = 0; j < 8; ++j) {
            int k = q * 8 + j;
            bwc[hf][j] = (__bf16)Wc[k * HID + hf * 16 + cl];
        }
        bias[hf] = B[hf * 16 + cl] + Bc[hf * 16 + cl];
    }

    const float4* x4 = (const float4*)p.x;
    const float4* h4 = (const float4*)p.h;
    const int x4_lim = p.n * F_IN / 4;   // 165*n divisible by 4 for n=500000
    const int h4_lim = p.n * HID / 4;

    for (int tile = blockIdx.x; tile < p.ntiles; tile += gridDim.x) {
        const int row0 = tile * 64;
        __syncthreads();   // protect sg reads of previous iteration vs sx writes

        // ---- stage x tile [64][165] fp32 -> bf16 LDS, swizzled, pad K to 192 ----
        {
            int base4 = tile * 2640;            // 64*165/4 float4 per tile
            for (int i = tid; i < 2640; i += 256) {
                int g4 = base4 + i;
                float4 v = {0.f, 0.f, 0.f, 0.f};
                if (g4 < x4_lim) v = x4[g4];
                float vals[4] = {v.x, v.y, v.z, v.w};
                int e0 = i * 4;
#pragma unroll
                for (int j = 0; j < 4; ++j) {
                    int e  = e0 + j;
                    int rr = e / 165;
                    int cc = e - rr * 165;
                    int off = (rr * 384 + cc * 2) ^ ((rr & 7) << 4);
                    sx[off >> 1] = (__bf16)vals[j];
                }
            }
            // zero-pad cols 165..191
            for (int i = tid; i < 64 * 27; i += 256) {
                int rr = i / 27;
                int cc = 165 + (i - rr * 27);
                int off = (rr * 384 + cc * 2) ^ ((rr & 7) << 4);
                sx[off >> 1] = (__bf16)0.f;
            }
        }
        // ---- stage h tile [64][32] -> bf16 LDS, swizzled ----
        {
            int hb4 = tile * 512;
            for (int i = tid; i < 512; i += 256) {
                int g4 = hb4 + i;
                float4 v = {0.f, 0.f, 0.f, 0.f};
                if (g4 < h4_lim) v = h4[g4];
                float vals[4] = {v.x, v.y, v.z, v.w};
                int e0 = i * 4;
                int rr = e0 >> 5, cc = e0 & 31;
#pragma unroll
                for (int j = 0; j < 4; ++j) {
                    int off = (rr * 64 + (cc + j) * 2) ^ ((rr & 7) << 4);
                    sh[off >> 1] = (__bf16)vals[j];
                }
            }
        }
        __syncthreads();

        // ---- MFMA: acc[rt][hf] = x_tile @ W + h_tile @ Wc (per-wave gate) ----
        f32x4 acc[4][2];
#pragma unroll
        for (int rt = 0; rt < 4; ++rt)
#pragma unroll
            for (int hf = 0; hf < 2; ++hf)
                acc[rt][hf] = (f32x4){0.f, 0.f, 0.f, 0.f};

#pragma unroll
        for (int ks = 0; ks < 6; ++ks) {
#pragma unroll
            for (int rt = 0; rt < 4; ++rt) {
                int row = rt * 16 + cl;
                int off = (row * 384 + ks * 64 + q * 16) ^ ((row & 7) << 4);
                bf16x8 a = *(const bf16x8*)(smem + off);
                acc[rt][0] = __builtin_amdgcn_mfma_f32_16x16x32_bf16(a, bw[ks][0], acc[rt][0], 0, 0, 0);
                acc[rt][1] = __builtin_amdgcn_mfma_f32_16x16x32_bf16(a, bw[ks][1], acc[rt][1], 0, 0, 0);
            }
        }
#pragma unroll
        for (int rt = 0; rt < 4; ++rt) {
            int row = rt * 16 + cl;
            int off = (row * 64 + q * 16) ^ ((row & 7) << 4);
            bf16x8 a = *(const bf16x8*)(smem + SH_OFF + off);
            acc[rt][0] = __builtin_amdgcn_mfma_f32_16x16x32_bf16(a, bwc[0], acc[rt][0], 0, 0, 0);
            acc[rt][1] = __builtin_amdgcn_mfma_f32_16x16x32_bf16(a, bwc[1], acc[rt][1], 0, 0, 0);
        }
        __syncthreads();   // all LDS reads done before gate buffer aliases sx/sh

        // ---- activate + write gates to LDS [4][64][33] ----
        // D layout: col = cl, row = 4*q + jj (within 16x16 tile)
#pragma unroll
        for (int rt = 0; rt < 4; ++rt)
#pragma unroll
            for (int hf = 0; hf < 2; ++hf)
#pragma unroll
                for (int jj = 0; jj < 4; ++jj) {
                    float pre = acc[rt][hf][jj] + bias[hf];
                    float v = is_tanh_gate ? fast_tanh(pre) : fast_sigmoid(pre);
                    sg[w * 2112 + (rt * 16 + 4 * q + jj) * 33 + hf * 16 + cl] = v;
                }
        __syncthreads();

        // ---- elementwise epilogue: c0, h0, classifier y ----
        {
            int r  = tid >> 2;          // row in tile
            int cb = (tid & 3) * 8;     // col base
            int grow = row0 + r;
            if (grow < p.n) {
                const float* cptr = p.c + (long)grow * HID + cb;
                float4 cA = *(const float4*)cptr;
                float4 cB = *(const float4*)(cptr + 4);
                float cv[8] = {cA.x, cA.y, cA.z, cA.w, cB.x, cB.y, cB.z, cB.w};
                float h0v[8], c0v[8];
                float y0 = 0.f, y1 = 0.f;
#pragma unroll
                for (int j = 0; j < 8; ++j) {
                    int cc = cb + j;
                    float iv = sg[0 * 2112 + r * 33 + cc];
                    float fv = sg[1 * 2112 + r * 33 + cc];
                    float gv = sg[2 * 2112 + r * 33 + cc];
                    float ov = sg[3 * 2112 + r * 33 + cc];
                    float c0 = fv * cv[j] + iv * gv;
                    float th = fast_tanh(c0);
                    float h0 = ov * th;
                    c0v[j] = c0;
                    h0v[j] = h0;
                    float rl = fmaxf(h0, 0.f);
                    y0 += rl * p.Wl[cc * 2 + 0];
                    y1 += rl * p.Wl[cc * 2 + 1];
                }
                float4 oh = {h0v[0], h0v[1], h0v[2], h0v[3]};
                float4 oh2 = {h0v[4], h0v[5], h0v[6], h0v[7]};
                float4 oc = {c0v[0], c0v[1], c0v[2], c0v[3]};
                float4 oc2 = {c0v[4], c0v[5], c0v[6], c0v[7]};
                float* hp = p.h0o + (long)grow * HID + cb;
                float* cp = p.c0o + (long)grow * HID + cb;
                *(float4*)hp = oh;
                *(float4*)(hp + 4) = oh2;
                *(float4*)cp = oc;
                *(float4*)(cp + 4) = oc2;
                // reduce y over the 4 threads of this row group
                y0 += __shfl_xor(y0, 1); y0 += __shfl_xor(y0, 2);
                y1 += __shfl_xor(y1, 1); y1 += __shfl_xor(y1, 2);
                if ((tid & 3) == 0) {
                    p.y[(long)grow * 2 + 0] = y0 + p.bl[0];
                    p.y[(long)grow * 2 + 1] = y1 + p.bl[1];
                }
            }
        }
    }
}

extern "C" void kernel_launch(void* const* d_in, const int* in_sizes, int n_in,
                              void* d_out, int out_size, void* d_ws, size_t ws_size,
                              hipStream_t stream) {
    KParams p;
    p.x   = (const float*)d_in[0];
    // d_in[1] edge_index, d_in[2] edge_weight: unused (ChebConv K=1)
    p.h   = (const float*)d_in[3];
    p.c   = (const float*)d_in[4];
    p.W0  = (const float*)d_in[5];
    p.W1  = (const float*)d_in[6];
    p.W2  = (const float*)d_in[7];
    p.W3  = (const float*)d_in[8];
    p.b0  = (const float*)d_in[9];
    p.b1  = (const float*)d_in[10];
    p.b2  = (const float*)d_in[11];
    p.b3  = (const float*)d_in[12];
    p.Wc0 = (const float*)d_in[13];
    p.Wc1 = (const float*)d_in[14];
    p.Wc2 = (const float*)d_in[15];
    p.Wc3 = (const float*)d_in[16];
    p.bc0 = (const float*)d_in[17];
    p.bc1 = (const float*)d_in[18];
    p.bc2 = (const float*)d_in[19];
    p.bc3 = (const float*)d_in[20];
    p.Wl  = (const float*)d_in[21];
    p.bl  = (const float*)d_in[22];

    const int n = in_sizes[0] / F_IN;   // 500000
    p.n = n;
    p.ntiles = (n + 63) / 64;

    float* out = (float*)d_out;
    p.y   = out;
    p.h0o = out + (long)n * 2;
    p.c0o = out + (long)n * 2 + (long)n * HID;

    dim3 grid(2048), block(256);
    hipLaunchKernelGGL(gclstm_kernel, grid, block, 0, stream, p);
}